// Round 8
// baseline (444.464 us; speedup 1.0000x reference)
//
#include <hip/hip_runtime.h>
#include <hip/hip_bf16.h>
#include <math.h>

#define BDIM 4
#define VDIM 8
#define NDIM 256
#define CDIM 768
#define HDIM 12
#define DHE  64
#define C3   (3*CDIM)
#define ROWS (BDIM*VDIM*NDIM)
#define KEYS (VDIM*NDIM)   // 2048

typedef __attribute__((ext_vector_type(8))) short short8;   // 8 bf16 = 4 VGPR
typedef __attribute__((ext_vector_type(4))) float float4v;  // MFMA acc

__device__ inline unsigned short f2bf(float f) {
    unsigned int u = __builtin_bit_cast(unsigned int, f);
    u += 0x7fffu + ((u >> 16) & 1u);   // RNE
    return (unsigned short)(u >> 16);
}

// ---------------------------------------------------------------------------
// fp32 -> bf16 cast, vectorized (n4 = #float4 groups)
// ---------------------------------------------------------------------------
__global__ void cast_bf16_kernel(const float* __restrict__ src,
                                 unsigned short* __restrict__ dst, int n4) {
    int i = blockIdx.x * blockDim.x + threadIdx.x;
    const int stride = gridDim.x * blockDim.x;
    for (; i < n4; i += stride) {
        float4 f = ((const float4*)src)[i];
        ushort4 o;
        o.x = f2bf(f.x); o.y = f2bf(f.y); o.z = f2bf(f.z); o.w = f2bf(f.w);
        ((ushort4*)dst)[i] = o;
    }
}

// ---------------------------------------------------------------------------
// bf16 MFMA GEMM for QKV proj (round-5 known-good: single-barrier staging;
// R6 DMA and R7 pipelining both regressed this kernel — do not touch).
// ---------------------------------------------------------------------------
__global__ __launch_bounds__(256) void gemm_qkv_mfma(
    const unsigned short* __restrict__ A,   // [8192][768] bf16
    const unsigned short* __restrict__ W,   // [2304][768] bf16
    const float* __restrict__ bias,
    unsigned short* __restrict__ out)       // [8192][2304] bf16
{
    __shared__ unsigned short As[4][128][8];
    __shared__ unsigned short Ws[4][128][8];
    const int t = threadIdx.x;
    const int wave = t >> 6, lane = t & 63;
    const int m = lane & 15, quad = lane >> 4;
    const int wr = (wave >> 1) * 64, wc = (wave & 1) * 64;
    const int row0 = blockIdx.y * 128, col0 = blockIdx.x * 128;

    float4v acc[4][4] = {};

    for (int k0 = 0; k0 < CDIM; k0 += 32) {
        #pragma unroll
        for (int i = 0; i < 2; i++) {
            const int c = t + 256 * i;
            const int r = c >> 2, ko = (c & 3) << 3;
            *(uint4*)&As[ko >> 3][r][0] =
                *(const uint4*)&A[(size_t)(row0 + r) * CDIM + k0 + ko];
            *(uint4*)&Ws[ko >> 3][r][0] =
                *(const uint4*)&W[(size_t)(col0 + r) * CDIM + k0 + ko];
        }
        __syncthreads();
        short8 a[4], b[4];
        #pragma unroll
        for (int rt = 0; rt < 4; rt++) a[rt] = *(const short8*)&As[quad][wr + rt * 16 + m][0];
        #pragma unroll
        for (int ct = 0; ct < 4; ct++) b[ct] = *(const short8*)&Ws[quad][wc + ct * 16 + m][0];
        #pragma unroll
        for (int rt = 0; rt < 4; rt++)
            #pragma unroll
            for (int ct = 0; ct < 4; ct++)
                acc[rt][ct] = __builtin_amdgcn_mfma_f32_16x16x32_bf16(
                    a[rt], b[ct], acc[rt][ct], 0, 0, 0);
        __syncthreads();
    }

    #pragma unroll
    for (int ct = 0; ct < 4; ct++) {
        const int col = col0 + wc + ct * 16 + m;
        const float bv = bias[col];
        #pragma unroll
        for (int rt = 0; rt < 4; rt++) {
            const size_t row = (size_t)row0 + wr + rt * 16 + quad * 4;
            #pragma unroll
            for (int r = 0; r < 4; r++)
                out[(row + r) * C3 + col] = f2bf(acc[rt][ct][r] + bv);
        }
    }
}

// ---------------------------------------------------------------------------
// V transpose: qkv v-part [b][key 2048][h][64] -> vT [b][h][64][2048]
// ---------------------------------------------------------------------------
__global__ __launch_bounds__(256) void transpose_v(
    const unsigned short* __restrict__ qkv, unsigned short* __restrict__ vT)
{
    __shared__ unsigned short T[64][72];
    const int kt = blockIdx.x, h = blockIdx.y, b = blockIdx.z;
    const int t = threadIdx.x;
    #pragma unroll
    for (int i = 0; i < 2; i++) {
        const int key = i * 32 + (t >> 3);
        const int dc = t & 7;
        const size_t row = (size_t)(b * KEYS + kt * 64 + key);
        *(uint4*)&T[key][dc * 8] =
            *(const uint4*)&qkv[row * C3 + 2 * CDIM + h * DHE + dc * 8];
    }
    __syncthreads();
    #pragma unroll
    for (int i = 0; i < 2; i++) {
        const int d = i * 32 + (t >> 3);
        const int kg = t & 7;
        unsigned short tmp[8];
        #pragma unroll
        for (int j = 0; j < 8; j++) tmp[j] = T[kg * 8 + j][d];
        *(uint4*)&vT[((size_t)((b * HDIM + h) * DHE + d)) * KEYS + kt * 64 + kg * 8] =
            *(uint4*)tmp;
    }
}

// ---------------------------------------------------------------------------
// MFMA flash attention, round 8: BARRIER-FREE wave-private staging.
// Each wave stages its own 32-key K/V chunk into its own LDS region, so
// there is no __syncthreads anywhere -> no vmcnt(0) barrier drains.
// Prefetch loads for chunk k+1 are issued right after the LDS stores of
// chunk k; the in-order per-wave DS/VM pipes give correctness, and the
// stores of k+1 wait only for their own loads (which had the whole compute
// phase of chunk k to land, L2-hot via the XCD swizzle).
// LDS per wave: Ks 4KB + Vs 4KB + Ps 2.5KB = 10.5KB; x4 waves = 42KB ->
// 3 blocks/CU. All frag read/write patterns conflict-free (or 2-way=free).
// ---------------------------------------------------------------------------
__global__ __launch_bounds__(256, 3) void attn_mfma(
    const unsigned short* __restrict__ qkv,  // [8192][2304] bf16
    const unsigned short* __restrict__ vT,   // [4][12][64][2048] bf16
    const int* __restrict__ is_ref,
    unsigned short* __restrict__ ctx)        // [8192][768] bf16
{
    const int gid = blockIdx.x;
    const int xcd = gid & 7;
    const int slot = gid >> 3;               // 0..95
    const int grp = xcd * 6 + (slot >> 4);   // 0..47 = (b,h)
    const int sub = slot & 15;               // 0..15 = (half,v)
    const int b = grp / HDIM, h = grp % HDIM;
    const int v = sub & 7, half = sub >> 3;

    const int t = threadIdx.x, wave = t >> 6, lane = t & 63;
    const int m = lane & 15, quad = lane >> 4;
    const int n0 = half * 128 + wave * 32;

    __shared__ unsigned short Ks[4][32][64];  // [wave][key][dim], dg^=key&7
    __shared__ unsigned short Vs[4][64][32];  // [wave][dim][key], kg^=dim&3
    __shared__ unsigned short Ps[4][32][40];  // [wave][query][key], stride 40

    const int my_ref = is_ref[b * VDIM + v];
    unsigned amask = 0;
    #pragma unroll
    for (int w = 0; w < VDIM; w++)
        if ((is_ref[b * VDIM + w] != 0) ^ (my_ref != 0)) amask |= 1u << w;
    const int nChunks = 8 * __popc(amask);   // 32-key chunks

    const float c1 = 0.18033688f;  // 0.125 * log2(e)

    // Q A-frags: A[m][k=quad*8+j], two 32-dim K-steps
    short8 aq[2][2];
    #pragma unroll
    for (int rt = 0; rt < 2; rt++) {
        const size_t row = (size_t)((b * VDIM + v) * NDIM) + n0 + rt * 16 + m;
        #pragma unroll
        for (int ks = 0; ks < 2; ks++)
            aq[rt][ks] = *(const short8*)&qkv[row * C3 + h * DHE + ks * 32 + quad * 8];
    }

    float rs[2][4] = {};
    float4v O[2][4] = {};

    // per-wave staging coords
    const int k_key = lane >> 3, k_dg = lane & 7;   // K: key = i*8 + k_key
    const int v_dl  = lane >> 2, v_kg = lane & 3;   // V: dim = i*16 + v_dl

    const unsigned short* vTb = vT + ((size_t)(b * HDIM + h) * DHE) * KEYS;

    uint4 kreg[4], vreg[4];
    unsigned rem = amask;
    int wcur = __builtin_ffs((int)rem) - 1;
    int sub8 = 0;

    if (nChunks > 0) {   // preload chunk 0
        const unsigned short* kb =
            qkv + (size_t)((b * VDIM + wcur) * NDIM) * C3 + CDIM + h * DHE;
        #pragma unroll
        for (int i = 0; i < 4; i++)
            kreg[i] = *(const uint4*)&kb[(size_t)(i * 8 + k_key) * C3 + k_dg * 8];
        #pragma unroll
        for (int i = 0; i < 4; i++)
            vreg[i] = *(const uint4*)&vTb[(size_t)(i * 16 + v_dl) * KEYS
                                          + wcur * NDIM + v_kg * 8];
    }

    for (int ci = 0; ci < nChunks; ci++) {
        // stage current chunk (waits only this wave's own loads)
        #pragma unroll
        for (int i = 0; i < 4; i++) {
            const int key = i * 8 + k_key;
            *(uint4*)&Ks[wave][key][(k_dg ^ (key & 7)) * 8] = kreg[i];
        }
        #pragma unroll
        for (int i = 0; i < 4; i++) {
            const int d = i * 16 + v_dl;
            *(uint4*)&Vs[wave][d][(v_kg ^ (d & 3)) * 8] = vreg[i];
        }

        // issue next chunk's loads: they fly across this chunk's compute
        if (ci + 1 < nChunks) {
            int wn = wcur, sn = sub8 + 1;
            if (sn == 8) {
                unsigned r2 = rem & (rem - 1);
                wn = __builtin_ffs((int)r2) - 1; sn = 0;
            }
            const int m0n = sn * 32;
            const unsigned short* kb =
                qkv + (size_t)((b * VDIM + wn) * NDIM + m0n) * C3 + CDIM + h * DHE;
            #pragma unroll
            for (int i = 0; i < 4; i++)
                kreg[i] = *(const uint4*)&kb[(size_t)(i * 8 + k_key) * C3 + k_dg * 8];
            #pragma unroll
            for (int i = 0; i < 4; i++)
                vreg[i] = *(const uint4*)&vTb[(size_t)(i * 16 + v_dl) * KEYS
                                              + wn * NDIM + m0n + v_kg * 8];
        }

        // S = Q K^T over 32 keys -> exp2 -> Ps
        #pragma unroll
        for (int nt = 0; nt < 2; nt++) {
            const short8 bk0 = *(const short8*)&Ks[wave][nt * 16 + m][(quad ^ (m & 7)) * 8];
            const short8 bk1 = *(const short8*)&Ks[wave][nt * 16 + m][((4 + quad) ^ (m & 7)) * 8];
            #pragma unroll
            for (int rt = 0; rt < 2; rt++) {
                float4v s = {};
                s = __builtin_amdgcn_mfma_f32_16x16x32_bf16(aq[rt][0], bk0, s, 0, 0, 0);
                s = __builtin_amdgcn_mfma_f32_16x16x32_bf16(aq[rt][1], bk1, s, 0, 0, 0);
                #pragma unroll
                for (int r = 0; r < 4; r++) {
                    const float p = __builtin_amdgcn_exp2f(s[r] * c1);
                    rs[rt][r] += p;
                    Ps[wave][rt * 16 + quad * 4 + r][nt * 16 + m] = f2bf(p);
                }
            }
        }

        // O += P @ V   (one K=32 step; wave-private Ps, in-order DS pipe)
        const short8 ap0 = *(const short8*)&Ps[wave][m][quad * 8];
        const short8 ap1 = *(const short8*)&Ps[wave][16 + m][quad * 8];
        #pragma unroll
        for (int ct = 0; ct < 4; ct++) {
            const short8 bv = *(const short8*)&Vs[wave][ct * 16 + m][(quad ^ (m & 3)) * 8];
            O[0][ct] = __builtin_amdgcn_mfma_f32_16x16x32_bf16(ap0, bv, O[0][ct], 0, 0, 0);
            O[1][ct] = __builtin_amdgcn_mfma_f32_16x16x32_bf16(ap1, bv, O[1][ct], 0, 0, 0);
        }

        if (++sub8 == 8) { rem &= rem - 1; wcur = __builtin_ffs((int)rem) - 1; sub8 = 0; }
    }

    // final: reduce l over the 16 m-lanes, normalize, write
    #pragma unroll
    for (int rt = 0; rt < 2; rt++) {
        float inv[4];
        #pragma unroll
        for (int r = 0; r < 4; r++) {
            float x = rs[rt][r];
            #pragma unroll
            for (int off = 1; off < 16; off <<= 1)
                x += __shfl_xor(x, off, 64);
            inv[r] = (x > 0.f) ? 1.f / x : 0.f;
        }
        const size_t rowg = (size_t)((b * VDIM + v) * NDIM) + n0 + rt * 16 + quad * 4;
        #pragma unroll
        for (int ct = 0; ct < 4; ct++)
            #pragma unroll
            for (int r = 0; r < 4; r++)
                ctx[(rowg + r) * CDIM + h * DHE + ct * 16 + m] = f2bf(O[rt][ct][r] * inv[r]);
    }
}

// ---------------------------------------------------------------------------
// bf16 MFMA GEMM for out-proj (round-5 known-good).
// ---------------------------------------------------------------------------
__global__ __launch_bounds__(256) void gemm_out_mfma(
    const unsigned short* __restrict__ A,   // ctx_b [8192][768]
    const unsigned short* __restrict__ W,   // wout_b [768][768]
    const float* __restrict__ bias,
    const float* __restrict__ feats,
    const int* __restrict__ is_ref,
    float* __restrict__ out)                // [8192][768] fp32
{
    __shared__ unsigned short As[4][128][8];
    __shared__ unsigned short Ws[4][128][8];
    const int t = threadIdx.x;
    const int wave = t >> 6, lane = t & 63;
    const int m = lane & 15, quad = lane >> 4;
    const int wr = (wave >> 1) * 64, wc = (wave & 1) * 64;
    const int row0 = blockIdx.y * 128, col0 = blockIdx.x * 128;

    float4v acc[4][4] = {};

    for (int k0 = 0; k0 < CDIM; k0 += 32) {
        #pragma unroll
        for (int i = 0; i < 2; i++) {
            const int c = t + 256 * i;
            const int r = c >> 2, ko = (c & 3) << 3;
            *(uint4*)&As[ko >> 3][r][0] =
                *(const uint4*)&A[(size_t)(row0 + r) * CDIM + k0 + ko];
            *(uint4*)&Ws[ko >> 3][r][0] =
                *(const uint4*)&W[(size_t)(col0 + r) * CDIM + k0 + ko];
        }
        __syncthreads();
        short8 a[4], b[4];
        #pragma unroll
        for (int rt = 0; rt < 4; rt++) a[rt] = *(const short8*)&As[quad][wr + rt * 16 + m][0];
        #pragma unroll
        for (int ct = 0; ct < 4; ct++) b[ct] = *(const short8*)&Ws[quad][wc + ct * 16 + m][0];
        #pragma unroll
        for (int rt = 0; rt < 4; rt++)
            #pragma unroll
            for (int ct = 0; ct < 4; ct++)
                acc[rt][ct] = __builtin_amdgcn_mfma_f32_16x16x32_bf16(
                    a[rt], b[ct], acc[rt][ct], 0, 0, 0);
        __syncthreads();
    }

    const int bidx = row0 / (VDIM * NDIM);
    const int vidx = (row0 / NDIM) % VDIM;
    const int my = is_ref[bidx * VDIM + vidx];
    bool has = false;
    #pragma unroll
    for (int w = 0; w < VDIM; w++) has = has || (is_ref[bidx * VDIM + w] != my);

    #pragma unroll
    for (int ct = 0; ct < 4; ct++) {
        const int col = col0 + wc + ct * 16 + m;
        const float bv = bias[col];
        #pragma unroll
        for (int rt = 0; rt < 4; rt++) {
            const size_t row = (size_t)row0 + wr + rt * 16 + quad * 4;
            #pragma unroll
            for (int r = 0; r < 4; r++) {
                float o = acc[rt][ct][r] + bv;
                if (!has) o = feats[(row + r) * CDIM + col];
                out[(row + r) * CDIM + col] = o;
            }
        }
    }
}

extern "C" void kernel_launch(void* const* d_in, const int* in_sizes, int n_in,
                              void* d_out, int out_size, void* d_ws, size_t ws_size,
                              hipStream_t stream) {
    const float* feats = (const float*)d_in[0];
    const int*   is_ref = (const int*)d_in[1];
    const float* w_qkv = (const float*)d_in[2];
    const float* b_qkv = (const float*)d_in[3];
    const float* w_out = (const float*)d_in[4];
    const float* b_out = (const float*)d_in[5];
    float* out = (float*)d_out;

    unsigned short* feats_b = (unsigned short*)d_ws;            // 8192x768
    unsigned short* wqkv_b  = feats_b + (size_t)ROWS * CDIM;    // 2304x768
    unsigned short* wout_b  = wqkv_b + (size_t)C3 * CDIM;       // 768x768
    unsigned short* qkv_b   = wout_b + (size_t)CDIM * CDIM;     // 8192x2304
    unsigned short* vT      = qkv_b + (size_t)ROWS * C3;        // 4x12x64x2048
    unsigned short* ctx_b   = vT + (size_t)BDIM * HDIM * DHE * KEYS; // 8192x768

    cast_bf16_kernel<<<2048, 256, 0, stream>>>(feats, feats_b, ROWS * CDIM / 4);
    cast_bf16_kernel<<<1024, 256, 0, stream>>>(w_qkv, wqkv_b, C3 * CDIM / 4);
    cast_bf16_kernel<<<144, 256, 0, stream>>>(w_out, wout_b, CDIM * CDIM / 4);

    dim3 g1(C3 / 128, ROWS / 128);                              // 18 x 64
    gemm_qkv_mfma<<<g1, 256, 0, stream>>>(feats_b, wqkv_b, b_qkv, qkv_b);

    dim3 gt(KEYS / 64, HDIM, BDIM);                             // 32 x 12 x 4
    transpose_v<<<gt, 256, 0, stream>>>(qkv_b, vT);

    attn_mfma<<<dim3(768), 256, 0, stream>>>(qkv_b, vT, is_ref, ctx_b);

    dim3 g3(CDIM / 128, ROWS / 128);                            // 6 x 64
    gemm_out_mfma<<<g3, 256, 0, stream>>>(ctx_b, wout_b, b_out, feats, is_ref, out);
    (void)in_sizes; (void)n_in; (void)out_size; (void)ws_size;
}

// Round 10
// 299.894 us; speedup vs baseline: 1.4821x; 1.4821x over previous
//
#include <hip/hip_runtime.h>
#include <hip/hip_bf16.h>
#include <math.h>

#define BDIM 4
#define VDIM 8
#define NDIM 256
#define CDIM 768
#define HDIM 12
#define DHE  64
#define C3   (3*CDIM)
#define ROWS (BDIM*VDIM*NDIM)
#define KEYS (VDIM*NDIM)   // 2048

typedef __attribute__((ext_vector_type(8))) short short8;   // 8 bf16 = 4 VGPR
typedef __attribute__((ext_vector_type(4))) float float4v;  // MFMA acc

__device__ inline unsigned short f2bf(float f) {
    unsigned int u = __builtin_bit_cast(unsigned int, f);
    u += 0x7fffu + ((u >> 16) & 1u);   // RNE
    return (unsigned short)(u >> 16);
}

// packed f32x2 -> bf16x2 in a uint (low half = a, high half = b), RNE
__device__ __forceinline__ unsigned int pk2(float a, float b) {
    return (unsigned int)f2bf(a) | ((unsigned int)f2bf(b) << 16);
}

// 8 fp32 (two float4) -> uint4 of 8 bf16
__device__ __forceinline__ uint4 pk8(float4 a, float4 b) {
    uint4 r;
    r.x = pk2(a.x, a.y); r.y = pk2(a.z, a.w);
    r.z = pk2(b.x, b.y); r.w = pk2(b.z, b.w);
    return r;
}

// ---------------------------------------------------------------------------
// Fused QKV GEMM: qkv[8192 x 2304] = bf16(feats) @ bf16(w_qkv)^T + bias.
// fp32->bf16 casts folded into LDS staging (pk8 during stage) — no
// separate cast kernels/buffers. V col-blocks (col0 >= 1536) write the
// TRANSPOSED vT buffer directly (packed 4-key ushort4) and skip qkv, so
// the standalone transpose kernel is gone too.
// ---------------------------------------------------------------------------
__global__ __launch_bounds__(256) void gemm_qkv_mfma(
    const float* __restrict__ A32,   // feats [8192][768] fp32
    const float* __restrict__ W32,   // w_qkv [2304][768] fp32
    const float* __restrict__ bias,
    unsigned short* __restrict__ out,   // qkv [8192][2304] bf16 (Q,K only)
    unsigned short* __restrict__ vT)    // [4][12][64][2048] bf16
{
    __shared__ unsigned short As[4][128][8];
    __shared__ unsigned short Ws[4][128][8];
    const int t = threadIdx.x;
    const int wave = t >> 6, lane = t & 63;
    const int m = lane & 15, quad = lane >> 4;
    const int wr = (wave >> 1) * 64, wc = (wave & 1) * 64;
    const int row0 = blockIdx.y * 128, col0 = blockIdx.x * 128;

    float4v acc[4][4] = {};

    for (int k0 = 0; k0 < CDIM; k0 += 32) {
        #pragma unroll
        for (int i = 0; i < 2; i++) {
            const int c = t + 256 * i;
            const int r = c >> 2, ko = (c & 3) << 3;
            const float* ap = &A32[(size_t)(row0 + r) * CDIM + k0 + ko];
            const float* wp = &W32[(size_t)(col0 + r) * CDIM + k0 + ko];
            *(uint4*)&As[ko >> 3][r][0] =
                pk8(*(const float4*)ap, *(const float4*)(ap + 4));
            *(uint4*)&Ws[ko >> 3][r][0] =
                pk8(*(const float4*)wp, *(const float4*)(wp + 4));
        }
        __syncthreads();
        short8 a[4], b[4];
        #pragma unroll
        for (int rt = 0; rt < 4; rt++) a[rt] = *(const short8*)&As[quad][wr + rt * 16 + m][0];
        #pragma unroll
        for (int ct = 0; ct < 4; ct++) b[ct] = *(const short8*)&Ws[quad][wc + ct * 16 + m][0];
        #pragma unroll
        for (int rt = 0; rt < 4; rt++)
            #pragma unroll
            for (int ct = 0; ct < 4; ct++)
                acc[rt][ct] = __builtin_amdgcn_mfma_f32_16x16x32_bf16(
                    a[rt], b[ct], acc[rt][ct], 0, 0, 0);
        __syncthreads();
    }

    if (col0 < 2 * CDIM) {
        // Q/K epilogue -> qkv
        #pragma unroll
        for (int ct = 0; ct < 4; ct++) {
            const int col = col0 + wc + ct * 16 + m;
            const float bv = bias[col];
            #pragma unroll
            for (int rt = 0; rt < 4; rt++) {
                const size_t row = (size_t)row0 + wr + rt * 16 + quad * 4;
                #pragma unroll
                for (int r = 0; r < 4; r++)
                    out[(row + r) * C3 + col] = f2bf(acc[rt][ct][r] + bv);
            }
        }
    } else {
        // V epilogue -> transposed vT (4 consecutive keys per lane -> 8B)
        #pragma unroll
        for (int ct = 0; ct < 4; ct++) {
            const int vcol = col0 + wc + ct * 16 + m - 2 * CDIM;
            const int h = vcol >> 6, d = vcol & 63;
            const float bv = bias[col0 + wc + ct * 16 + m];
            #pragma unroll
            for (int rt = 0; rt < 4; rt++) {
                const int row = row0 + wr + rt * 16 + quad * 4;
                const int bidx = row >> 11, key = row & 2047;
                ushort4 pkv;
                pkv.x = f2bf(acc[rt][ct][0] + bv);
                pkv.y = f2bf(acc[rt][ct][1] + bv);
                pkv.z = f2bf(acc[rt][ct][2] + bv);
                pkv.w = f2bf(acc[rt][ct][3] + bv);
                *(ushort4*)&vT[((size_t)(bidx * HDIM + h) * DHE + d) * KEYS + key] = pkv;
            }
        }
    }
}

// ---------------------------------------------------------------------------
// MFMA flash attention, round 10 = R5/R6 two-barrier structure (known-best)
// with the S^T softmax path:
//   S^T = K Q^T  (operand swap; K/Q fragment loads UNCHANGED — K is
//   natively A-shaped, Q natively B-shaped). C layout then gives each lane
//   4 CONSECUTIVE KEYS of one query -> P packed via pk2 and written as
//   16 x ds_write_b64 per chunk-half (was 64 x ds_write_b16), and the
//   l-reduction is 2 shuffles (was a 16-lane butterfly).
// XCD-grouped block swizzle kept (R6: FETCH 164->97 MB, free).
// ---------------------------------------------------------------------------
__global__ __launch_bounds__(256, 3) void attn_mfma(
    const unsigned short* __restrict__ qkv,  // [8192][2304] bf16 (Q,K)
    const unsigned short* __restrict__ vT,   // [4][12][64][2048] bf16
    const int* __restrict__ is_ref,
    unsigned short* __restrict__ ctx)        // [8192][768] bf16
{
    const int gid = blockIdx.x;
    const int xcd = gid & 7;
    const int slot = gid >> 3;               // 0..95
    const int grp = xcd * 6 + (slot >> 4);   // 0..47 = (b,h)
    const int sub = slot & 15;               // 0..15 = (half,v)
    const int b = grp / HDIM, h = grp % HDIM;
    const int v = sub & 7, half = sub >> 3;

    const int t = threadIdx.x, wave = t >> 6, lane = t & 63;
    const int m = lane & 15, quad = lane >> 4;
    const int n0 = half * 128 + wave * 32;

    __shared__ unsigned short Ks[128][64];   // [key][dim], dg' = dg ^ (key&7)
    __shared__ unsigned short Vs[64][128];   // [dim][key], kg' = kg ^ (dim&15)
    __shared__ unsigned short Ps[4][32][72]; // [wave][query][64-key half]

    const int my_ref = is_ref[b * VDIM + v];
    unsigned amask = 0;
    #pragma unroll
    for (int w = 0; w < VDIM; w++)
        if ((is_ref[b * VDIM + w] != 0) ^ (my_ref != 0)) amask |= 1u << w;
    const int nChunks = 2 * __popc(amask);

    const float c1 = 0.18033688f;  // 0.125 * log2(e)

    // Q B-frags: B[n=query=m][k=quad*8+j], two 32-dim K-steps
    short8 aq[2][2];
    #pragma unroll
    for (int qt = 0; qt < 2; qt++) {
        const size_t row = (size_t)((b * VDIM + v) * NDIM) + n0 + qt * 16 + m;
        #pragma unroll
        for (int ks = 0; ks < 2; ks++)
            aq[qt][ks] = *(const short8*)&qkv[row * C3 + h * DHE + ks * 32 + quad * 8];
    }

    float rs[2] = {0.f, 0.f};     // per-lane l partial, query = qt*16 + m
    float4v O[2][4] = {};

    // staging thread coords
    const int k_key = t >> 3, k_dg = t & 7;    // key = i*32 + k_key
    const int v_dim = t >> 4, v_kg = t & 15;   // dim = i*16 + v_dim

    const unsigned short* vTb = vT + (size_t)(b * HDIM + h) * DHE * KEYS;

    uint4 kreg[4], vreg[4];
    unsigned rem = amask;
    int wcur = __builtin_ffs((int)rem) - 1;

    if (nChunks > 0) {
        const unsigned short* kb =
            qkv + (size_t)((b * VDIM + wcur) * NDIM) * C3 + CDIM + h * DHE;
        #pragma unroll
        for (int i = 0; i < 4; i++)
            kreg[i] = *(const uint4*)&kb[(size_t)(i * 32 + k_key) * C3 + k_dg * 8];
        #pragma unroll
        for (int i = 0; i < 4; i++)
            vreg[i] = *(const uint4*)&vTb[(size_t)(i * 16 + v_dim) * KEYS
                                          + wcur * NDIM + v_kg * 8];
    }

    for (int ci = 0; ci < nChunks; ci++) {
        __syncthreads();   // prev chunk's LDS reads complete
        #pragma unroll
        for (int i = 0; i < 4; i++)
            *(uint4*)&Ks[i * 32 + k_key][(k_dg ^ (k_key & 7)) * 8] = kreg[i];
        #pragma unroll
        for (int i = 0; i < 4; i++)
            *(uint4*)&Vs[i * 16 + v_dim][(v_kg ^ v_dim) * 8] = vreg[i];

        if (ci + 1 < nChunks) {   // prefetch next chunk into regs
            int wn, m0n;
            if ((ci & 1) == 0) { wn = wcur; m0n = 128; }
            else {
                unsigned r2 = rem & (rem - 1);
                wn = __builtin_ffs((int)r2) - 1; m0n = 0;
            }
            const unsigned short* kb =
                qkv + (size_t)((b * VDIM + wn) * NDIM + m0n) * C3 + CDIM + h * DHE;
            #pragma unroll
            for (int i = 0; i < 4; i++)
                kreg[i] = *(const uint4*)&kb[(size_t)(i * 32 + k_key) * C3 + k_dg * 8];
            #pragma unroll
            for (int i = 0; i < 4; i++)
                vreg[i] = *(const uint4*)&vTb[(size_t)(i * 16 + v_dim) * KEYS
                                              + wn * NDIM + m0n + v_kg * 8];
        }
        __syncthreads();   // LDS tiles visible

        // two 64-key halves: S^T tiles -> packed Ps, then PV for that half
        #pragma unroll
        for (int hk = 0; hk < 2; hk++) {
            #pragma unroll
            for (int kt = 0; kt < 4; kt++) {
                const int nt = hk * 4 + kt;
                // A-frag = K (lane m = key within tile), same reads as before
                const short8 bk0 = *(const short8*)&Ks[nt * 16 + m][(quad ^ (m & 7)) * 8];
                const short8 bk1 = *(const short8*)&Ks[nt * 16 + m][((4 + quad) ^ (m & 7)) * 8];
                #pragma unroll
                for (int qt = 0; qt < 2; qt++) {
                    float4v s = {};
                    s = __builtin_amdgcn_mfma_f32_16x16x32_bf16(bk0, aq[qt][0], s, 0, 0, 0);
                    s = __builtin_amdgcn_mfma_f32_16x16x32_bf16(bk1, aq[qt][1], s, 0, 0, 0);
                    // s[r]: key = nt*16 + quad*4 + r, query = qt*16 + m
                    const float p0 = __builtin_amdgcn_exp2f(s[0] * c1);
                    const float p1 = __builtin_amdgcn_exp2f(s[1] * c1);
                    const float p2 = __builtin_amdgcn_exp2f(s[2] * c1);
                    const float p3 = __builtin_amdgcn_exp2f(s[3] * c1);
                    rs[qt] += (p0 + p1) + (p2 + p3);
                    uint2 pw;
                    pw.x = pk2(p0, p1);
                    pw.y = pk2(p2, p3);
                    *(uint2*)&Ps[wave][qt * 16 + m][kt * 16 + quad * 4] = pw;
                }
            }
            #pragma unroll
            for (int kk = 0; kk < 2; kk++) {
                const short8 ap0 = *(const short8*)&Ps[wave][m][kk * 32 + quad * 8];
                const short8 ap1 = *(const short8*)&Ps[wave][16 + m][kk * 32 + quad * 8];
                #pragma unroll
                for (int ct = 0; ct < 4; ct++) {
                    const short8 bv = *(const short8*)&Vs[ct * 16 + m]
                        [((hk * 8 + kk * 4 + quad) ^ m) * 8];
                    O[0][ct] = __builtin_amdgcn_mfma_f32_16x16x32_bf16(ap0, bv, O[0][ct], 0, 0, 0);
                    O[1][ct] = __builtin_amdgcn_mfma_f32_16x16x32_bf16(ap1, bv, O[1][ct], 0, 0, 0);
                }
            }
        }
        if (ci & 1) { rem &= rem - 1; wcur = __builtin_ffs((int)rem) - 1; }
    }

    // final: reduce l across the 4 quad-copies, broadcast to O rows, write
    #pragma unroll
    for (int qt = 0; qt < 2; qt++) {
        float x = rs[qt];
        x += __shfl_xor(x, 16, 64);
        x += __shfl_xor(x, 32, 64);
        const float inv = (x > 0.f) ? 1.f / x : 0.f;   // query = qt*16 + m
        float invq[4];
        #pragma unroll
        for (int r = 0; r < 4; r++)
            invq[r] = __shfl(inv, quad * 4 + r, 64);   // query = qt*16+quad*4+r
        const size_t rowg = (size_t)((b * VDIM + v) * NDIM) + n0 + qt * 16 + quad * 4;
        #pragma unroll
        for (int ct = 0; ct < 4; ct++)
            #pragma unroll
            for (int r = 0; r < 4; r++)
                ctx[(rowg + r) * CDIM + h * DHE + ct * 16 + m] = f2bf(O[qt][ct][r] * invq[r]);
    }
}

// ---------------------------------------------------------------------------
// Out-proj GEMM with fused fp32->bf16 W staging; fp32 out + passthrough.
// ---------------------------------------------------------------------------
__global__ __launch_bounds__(256) void gemm_out_mfma(
    const unsigned short* __restrict__ A,   // ctx_b [8192][768] bf16
    const float* __restrict__ W32,          // w_out [768][768] fp32
    const float* __restrict__ bias,
    const float* __restrict__ feats,
    const int* __restrict__ is_ref,
    float* __restrict__ out)                // [8192][768] fp32
{
    __shared__ unsigned short As[4][128][8];
    __shared__ unsigned short Ws[4][128][8];
    const int t = threadIdx.x;
    const int wave = t >> 6, lane = t & 63;
    const int m = lane & 15, quad = lane >> 4;
    const int wr = (wave >> 1) * 64, wc = (wave & 1) * 64;
    const int row0 = blockIdx.y * 128, col0 = blockIdx.x * 128;

    float4v acc[4][4] = {};

    for (int k0 = 0; k0 < CDIM; k0 += 32) {
        #pragma unroll
        for (int i = 0; i < 2; i++) {
            const int c = t + 256 * i;
            const int r = c >> 2, ko = (c & 3) << 3;
            *(uint4*)&As[ko >> 3][r][0] =
                *(const uint4*)&A[(size_t)(row0 + r) * CDIM + k0 + ko];
            const float* wp = &W32[(size_t)(col0 + r) * CDIM + k0 + ko];
            *(uint4*)&Ws[ko >> 3][r][0] =
                pk8(*(const float4*)wp, *(const float4*)(wp + 4));
        }
        __syncthreads();
        short8 a[4], b[4];
        #pragma unroll
        for (int rt = 0; rt < 4; rt++) a[rt] = *(const short8*)&As[quad][wr + rt * 16 + m][0];
        #pragma unroll
        for (int ct = 0; ct < 4; ct++) b[ct] = *(const short8*)&Ws[quad][wc + ct * 16 + m][0];
        #pragma unroll
        for (int rt = 0; rt < 4; rt++)
            #pragma unroll
            for (int ct = 0; ct < 4; ct++)
                acc[rt][ct] = __builtin_amdgcn_mfma_f32_16x16x32_bf16(
                    a[rt], b[ct], acc[rt][ct], 0, 0, 0);
        __syncthreads();
    }

    const int bidx = row0 / (VDIM * NDIM);
    const int vidx = (row0 / NDIM) % VDIM;
    const int my = is_ref[bidx * VDIM + vidx];
    bool has = false;
    #pragma unroll
    for (int w = 0; w < VDIM; w++) has = has || (is_ref[bidx * VDIM + w] != my);

    #pragma unroll
    for (int ct = 0; ct < 4; ct++) {
        const int col = col0 + wc + ct * 16 + m;
        const float bv = bias[col];
        #pragma unroll
        for (int rt = 0; rt < 4; rt++) {
            const size_t row = (size_t)row0 + wr + rt * 16 + quad * 4;
            #pragma unroll
            for (int r = 0; r < 4; r++) {
                float o = acc[rt][ct][r] + bv;
                if (!has) o = feats[(row + r) * CDIM + col];
                out[(row + r) * CDIM + col] = o;
            }
        }
    }
}

extern "C" void kernel_launch(void* const* d_in, const int* in_sizes, int n_in,
                              void* d_out, int out_size, void* d_ws, size_t ws_size,
                              hipStream_t stream) {
    const float* feats = (const float*)d_in[0];
    const int*   is_ref = (const int*)d_in[1];
    const float* w_qkv = (const float*)d_in[2];
    const float* b_qkv = (const float*)d_in[3];
    const float* w_out = (const float*)d_in[4];
    const float* b_out = (const float*)d_in[5];
    float* out = (float*)d_out;

    unsigned short* qkv_b = (unsigned short*)d_ws;              // 8192x2304
    unsigned short* vT    = qkv_b + (size_t)ROWS * C3;          // 4x12x64x2048
    unsigned short* ctx_b = vT + (size_t)BDIM * HDIM * DHE * KEYS; // 8192x768

    dim3 g1(C3 / 128, ROWS / 128);                              // 18 x 64
    gemm_qkv_mfma<<<g1, 256, 0, stream>>>(feats, w_qkv, b_qkv, qkv_b, vT);

    attn_mfma<<<dim3(768), 256, 0, stream>>>(qkv_b, vT, is_ref, ctx_b);

    dim3 g3(CDIM / 128, ROWS / 128);                            // 6 x 64
    gemm_out_mfma<<<g3, 256, 0, stream>>>(ctx_b, w_out, b_out, feats, is_ref, out);
    (void)in_sizes; (void)n_in; (void)out_size; (void)ws_size;
}